// Round 10
// baseline (172.313 us; speedup 1.0000x reference)
//
#include <hip/hip_runtime.h>
#include <hip/hip_fp16.h>

#define G 128

typedef _Float16 h2_t __attribute__((ext_vector_type(2)));

union U16 { uint4 u; h2_t h2[4]; };
union HV  { uint4 u; h2_t h2[4]; };

__device__ __forceinline__ float dot2f(h2_t a, h2_t b, float c) {
#if __has_builtin(__builtin_amdgcn_fdot2)
    return __builtin_amdgcn_fdot2(a, b, c, false);
#else
    return c + (float)a.x * (float)b.x + (float)a.y * (float)b.y;
#endif
}

__device__ __forceinline__ h2_t h2max(h2_t a, h2_t b) {
#if __has_builtin(__builtin_elementwise_max)
    return __builtin_elementwise_max(a, b);
#else
    h2_t r;
    r.x = a.x > b.x ? a.x : b.x;
    r.y = a.y > b.y ? a.y : b.y;
    return r;
#endif
}

__device__ __forceinline__ float dot4(float4 a, float4 b) {
    return a.x * b.x + a.y * b.y + a.z * b.z + a.w * b.w;
}

// ---------------------------------------------------------------------------
// Kernel P: pack weights to fp16 half2 (read later via uniform scalar loads).
//  w1h[tap*8 + p]       = (W1[tap][2p],   W1[tap][2p+1])          216 h2
//  w2h[t*32 + co*8 + p] = (W2[t][2p][co], W2[t][2p+1][co])        864 h2
// ---------------------------------------------------------------------------
__global__ void k_prep(const float* __restrict__ W1, const float* __restrict__ W2,
                       __half* __restrict__ w1h, __half* __restrict__ w2h)
{
    int i = blockIdx.x * 256 + threadIdx.x;
    if (i < 216) {
        int tap = i >> 3, p = i & 7;
        w1h[2 * i]     = __float2half(W1[tap * 16 + 2 * p]);
        w1h[2 * i + 1] = __float2half(W1[tap * 16 + 2 * p + 1]);
    }
    if (i < 864) {
        int t = i >> 5, r = i & 31, co = r >> 3, p = r & 7;
        w2h[2 * i]     = __float2half(W2[t * 64 + (2 * p) * 4 + co]);
        w2h[2 * i + 1] = __float2half(W2[t * 64 + (2 * p + 1) * 4 + co]);
    }
}

// ---------------------------------------------------------------------------
// Kernel A: fused conv1 (3x3x3, 1->16, SAME) + relu + m0-mask + 2x2x2 maxpool.
// Register-blocked: each thread owns one pooled voxel = 2x2x2 conv centers,
// whose taps span a 4x4x[-1..2] neighborhood. The 4x4 (z,y) rows are loaded
// ONCE as 1 ds_read_b64 + 1 ds_read_b32 each (32 LDS ops/thread; the R9
// version issued 216 ds_read_u16 + 216 packs — the LDS pipe was the
// co-limiter). Tile x-halo = 2 so row base half-index 2*tx is even
// (4-byte-aligned b64). All 1728 v_pk_fma run from registers with
// op_sel-foldable half broadcasts. Tile: z10 x y18 x x20 fp16 + mask.
// ---------------------------------------------------------------------------
__global__ __launch_bounds__(256)
void k_conv1_pool(const float* __restrict__ x, const int* __restrict__ occ,
                  const h2_t* __restrict__ w1h,
                  __half* __restrict__ h1p, float* __restrict__ m1)
{
    __shared__ _Float16      sx[10 * 18 * 20];   // [z][y][x], x-halo 2 left
    __shared__ unsigned char sm[10 * 18 * 20];

    const int bx = blockIdx.x, by = blockIdx.y;
    const int b  = blockIdx.z >> 4, zt = blockIdx.z & 15;
    const int tid = threadIdx.x;

    const int z0 = zt * 8 - 1, y0 = by * 16 - 1, x0 = bx * 16 - 2;
    const int base_b = b * G * G * G;

    #pragma unroll
    for (int r = 0; r < 15; ++r) {
        int i = r * 256 + tid;
        if (i < 3600) {
            int lz = i / 360, rr = i - lz * 360;
            int ly = rr / 20, lx = rr - ly * 20;
            int gz = z0 + lz, gy = y0 + ly, gx = x0 + lx;
            bool inb = (unsigned)gz < 128u && (unsigned)gy < 128u &&
                       (unsigned)gx < 128u;
            int oc = 1; float xv = 0.f;
            if (inb) {                 // two independent loads, both in flight
                int gi = base_b + (gz * G + gy) * G + gx;
                oc = occ[gi];
                xv = x[gi];
            }
            bool mm = inb && (oc == 0);
            sx[i] = mm ? (_Float16)xv : (_Float16)0.f;
            sm[i] = mm ? 1 : 0;
        }
    }
    __syncthreads();

    const int tx = tid & 7, ty = (tid >> 3) & 7, tz = tid >> 6;

    // ---- load the 4x4 rows (6 halves each) into registers ----
    // row (zz,yy) covers conv-x [2tx-2 .. 2tx+3]; tile half-index base =
    // (tile_z*18 + tile_y)*20 + 2tx with tile_z = 2tz+zz, tile_y = 2ty+yy.
    h2_t ra[4][4], rb[4][4], rc[4][4];
    #pragma unroll
    for (int zz = 0; zz < 4; ++zz)
    #pragma unroll
    for (int yy = 0; yy < 4; ++yy) {
        const _Float16* p = &sx[((2 * tz + zz) * 18 + (2 * ty + yy)) * 20 + 2 * tx];
        uint2 lo = *(const uint2*)p;        // ds_read_b64: halves 0..3
        unsigned hi = *(const unsigned*)(p + 4);  // ds_read_b32: halves 4..5
        union { unsigned u; h2_t h; } c0, c1, c2;
        c0.u = lo.x; c1.u = lo.y; c2.u = hi;
        ra[zz][yy] = c0.h; rb[zz][yy] = c1.h; rc[zz][yy] = c2.h;
    }

    const h2_t zero = (h2_t)(_Float16)0.f;
    h2_t best[8];
    #pragma unroll
    for (int c = 0; c < 8; ++c) best[c] = zero;
    int anym = 0;

    #pragma unroll
    for (int pos = 0; pos < 8; ++pos) {
        const int dz = pos >> 2, dy = (pos >> 1) & 1, dx = pos & 1;
        // center mask (tile coords: conv+offset, x-halo 2)
        const int cmz = 2 * tz + dz + 1, cmy = 2 * ty + dy + 1, cmx = 2 * tx + dx + 2;
        if (sm[(cmz * 18 + cmy) * 20 + cmx]) {
            anym = 1;
            h2_t acc[8];
            #pragma unroll
            for (int c = 0; c < 8; ++c) acc[c] = zero;
            #pragma unroll
            for (int kz = 0; kz < 3; ++kz)
            #pragma unroll
            for (int ky = 0; ky < 3; ++ky)
            #pragma unroll
            for (int kx = 0; kx < 3; ++kx) {
                const int zz = dz + kz, yy = dy + ky;
                const int hidx = dx + kx + 1;     // 1..4 within the 6-half row
                _Float16 v;
                if      (hidx == 1) v = ra[zz][yy].y;
                else if (hidx == 2) v = rb[zz][yy].x;
                else if (hidx == 3) v = rb[zz][yy].y;
                else                v = rc[zz][yy].x;
                h2_t v2 = {v, v};
                const h2_t* w = &w1h[((kz * 3 + ky) * 3 + kx) * 8];   // uniform
                #pragma unroll
                for (int c = 0; c < 8; ++c) acc[c] = v2 * w[c] + acc[c];
            }
            #pragma unroll
            for (int c = 0; c < 8; ++c) best[c] = h2max(best[c], h2max(acc[c], zero));
        }
    }

    const int pz = zt * 4 + tz, py = by * 8 + ty, px = bx * 8 + tx;
    const int vidx = ((b * 64 + pz) * 64 + py) * 64 + px;
    HV p0, p1;
    #pragma unroll
    for (int c = 0; c < 4; ++c) { p0.h2[c] = best[c]; p1.h2[c] = best[4 + c]; }
    uint4* o = (uint4*)&h1p[(size_t)vidx * 16];
    o[0] = p0.u;
    o[1] = p1.u;
    m1[vidx] = anym ? 1.f : 0.f;
}

// ---------------------------------------------------------------------------
// Kernel B: fused conv2 (3x3x3, 16->4) + relu + m1-mask + pool + FULL DECODER
// (tconv1 4->16 + relu, tconv2 16->1 + sigmoid, m2 gating). Unchanged from
// R9 — four different conv2/decoder variants all left total-within-noise;
// it is not the counter-visible bottleneck.
// ---------------------------------------------------------------------------
__global__ __launch_bounds__(256)
void k_conv2_dec(const __half* __restrict__ h1p, const float* __restrict__ m1,
                 const h2_t* __restrict__ w2h,
                 const float* __restrict__ Wt1, const float* __restrict__ Wt2,
                 float* __restrict__ out)
{
    __shared__ uint4  tile[1100];   // 10*10*11 voxels, 8ch fp16 = 17.6 KB
    __shared__ float4 wt1[128];     // Wt1: 512 floats
    __shared__ float4 wt2[32];      // Wt2: 128 floats
    __shared__ float4 sh_h[64];     // pooled h2 per parent
    __shared__ float  sh_m[64];     // pooled m2 per parent

    const int bx = blockIdx.x, by = blockIdx.y;
    const int b  = blockIdx.z >> 3, bz = blockIdx.z & 7;
    const int tid = threadIdx.x;

    if (tid < 128) wt1[tid] = ((const float4*)Wt1)[tid];
    if (tid < 32)  wt2[tid] = ((const float4*)Wt2)[tid];

    const int z0 = bz * 8 - 1, y0 = by * 8 - 1, x0 = bx * 8 - 1;

    const int dy = tid & 1, dz = (tid >> 1) & 1;
    const int qx = (tid >> 2) & 3, Y = (tid >> 4) & 3, Z = (tid >> 6) & 3;
    const int cx0 = 2 * qx, cy = 2 * Y + dy, cz = 2 * Z + dz;

    float acc[2][4] = {{0.f, 0.f, 0.f, 0.f}, {0.f, 0.f, 0.f, 0.f}};

    for (int h = 0; h < 2; ++h) {
        if (h) __syncthreads();
        #pragma unroll
        for (int it = 0; it < 5; ++it) {
            int g = it * 256 + tid;
            if (g < 1100) {
                int z = g / 110, r = g - z * 110, y = r / 11, xx = r - y * 11;
                int gz = z0 + z, gy = y0 + y, gx = x0 + xx;
                uint4 a = make_uint4(0u, 0u, 0u, 0u);
                if ((unsigned)gz < 64u && (unsigned)gy < 64u && (unsigned)gx < 64u)
                    a = ((const uint4*)&h1p[(size_t)(((b * 64 + gz) * 64 + gy) * 64 + gx) * 16])[h];
                tile[g] = a;
            }
        }
        __syncthreads();

        #pragma unroll
        for (int kz = 0; kz < 3; ++kz)
        #pragma unroll
        for (int ky = 0; ky < 3; ++ky) {
            const int rb = (cz + kz) * 110 + (cy + ky) * 11 + cx0;
            h2_t hp[4][4];
            #pragma unroll
            for (int xi = 0; xi < 4; ++xi) {
                U16 a; a.u = tile[rb + xi];
                #pragma unroll
                for (int p = 0; p < 4; ++p) hp[xi][p] = a.h2[p];
            }
            const int t3 = (kz * 3 + ky) * 3;
            #pragma unroll
            for (int kx = 0; kx < 3; ++kx) {
                const h2_t* w = w2h + (t3 + kx) * 32 + 4 * h;   // uniform -> s_load
                #pragma unroll
                for (int j = 0; j < 2; ++j) {
                    #pragma unroll
                    for (int co = 0; co < 4; ++co) {
                        float a = acc[j][co];
                        #pragma unroll
                        for (int p = 0; p < 4; ++p)
                            a = dot2f(hp[kx + j][p], w[co * 8 + p], a);
                        acc[j][co] = a;
                    }
                }
            }
        }
    }

    // ---- mask + relu + pool ----
    const int gcz = bz * 8 + cz, gcy = by * 8 + cy, gcx = bx * 8 + cx0;
    const float mv0 = m1[((b * 64 + gcz) * 64 + gcy) * 64 + gcx];
    const float mv1 = m1[((b * 64 + gcz) * 64 + gcy) * 64 + gcx + 1];
    float m = fmaxf(mv0, mv1);
    float r0 = fmaxf(fmaxf(acc[0][0], 0.f) * mv0, fmaxf(acc[1][0], 0.f) * mv1);
    float r1 = fmaxf(fmaxf(acc[0][1], 0.f) * mv0, fmaxf(acc[1][1], 0.f) * mv1);
    float r2 = fmaxf(fmaxf(acc[0][2], 0.f) * mv0, fmaxf(acc[1][2], 0.f) * mv1);
    float r3 = fmaxf(fmaxf(acc[0][3], 0.f) * mv0, fmaxf(acc[1][3], 0.f) * mv1);

    #pragma unroll
    for (int mask = 1; mask <= 2; mask <<= 1) {
        r0 = fmaxf(r0, __shfl_xor(r0, mask));
        r1 = fmaxf(r1, __shfl_xor(r1, mask));
        r2 = fmaxf(r2, __shfl_xor(r2, mask));
        r3 = fmaxf(r3, __shfl_xor(r3, mask));
        m  = fmaxf(m,  __shfl_xor(m,  mask));
    }
    if ((tid & 3) == 0) {
        int p = Z * 16 + Y * 4 + qx;
        sh_h[p] = make_float4(r0, r1, r2, r3);
        sh_m[p] = m;
    }
    __syncthreads();

    // ---- decoder phase: thread = (parent p, a, bb) ----
    {
        const int p  = tid >> 2;
        const int a  = (tid >> 1) & 1;
        const int bb = tid & 1;
        const int pZ = p >> 4, pY = (p >> 2) & 3, pq = p & 3;
        const int pz = bz * 4 + pZ, py = by * 4 + pY, pxq = bx * 4 + pq;

        const float mm = sh_m[p];
        const float4 hv = sh_h[p];

        const int b0q = ((((1 - a) * 2 + (1 - bb)) * 2) + 1) * 16;  // c=0 -> kc=1
        const int b1q = ((((1 - a) * 2 + (1 - bb)) * 2) + 0) * 16;  // c=1 -> kc=0
        float4 t0q[4], t1q[4];
        #pragma unroll
        for (int q = 0; q < 4; ++q) {
            float4 a0 = wt1[b0q + q],      a1 = wt1[b0q + 4 + q];
            float4 a2 = wt1[b0q + 8 + q],  a3 = wt1[b0q + 12 + q];
            float4 c0 = wt1[b1q + q],      c1 = wt1[b1q + 4 + q];
            float4 c2 = wt1[b1q + 8 + q],  c3 = wt1[b1q + 12 + q];
            float4 s0, s1;
            s0.x = hv.x * a0.x + hv.y * a1.x + hv.z * a2.x + hv.w * a3.x;
            s0.y = hv.x * a0.y + hv.y * a1.y + hv.z * a2.y + hv.w * a3.y;
            s0.z = hv.x * a0.z + hv.y * a1.z + hv.z * a2.z + hv.w * a3.z;
            s0.w = hv.x * a0.w + hv.y * a1.w + hv.z * a2.w + hv.w * a3.w;
            s1.x = hv.x * c0.x + hv.y * c1.x + hv.z * c2.x + hv.w * c3.x;
            s1.y = hv.x * c0.y + hv.y * c1.y + hv.z * c2.y + hv.w * c3.y;
            s1.z = hv.x * c0.z + hv.y * c1.z + hv.z * c2.z + hv.w * c3.z;
            s1.w = hv.x * c0.w + hv.y * c1.w + hv.z * c2.w + hv.w * c3.w;
            t0q[q] = make_float4(fmaxf(s0.x, 0.f), fmaxf(s0.y, 0.f),
                                 fmaxf(s0.z, 0.f), fmaxf(s0.w, 0.f));
            t1q[q] = make_float4(fmaxf(s1.x, 0.f), fmaxf(s1.y, 0.f),
                                 fmaxf(s1.z, 0.f), fmaxf(s1.w, 0.f));
        }

        #pragma unroll
        for (int e = 0; e < 2; ++e) {
            #pragma unroll
            for (int f = 0; f < 2; ++f) {
                const int d  = 4 * pz + 2 * a + e;
                const int hh = 4 * py + 2 * bb + f;
                const int be = ((1 - e) * 2 + (1 - f)) * 2;
                const float4* wg0 = &wt2[(be + 1) * 4];   // g=0 -> kg=1
                const float4* wg1 = &wt2[(be + 0) * 4];   // g=1 -> kg=0
                float s00 = dot4(t0q[0], wg0[0]) + dot4(t0q[1], wg0[1])
                          + dot4(t0q[2], wg0[2]) + dot4(t0q[3], wg0[3]);
                float s01 = dot4(t0q[0], wg1[0]) + dot4(t0q[1], wg1[1])
                          + dot4(t0q[2], wg1[2]) + dot4(t0q[3], wg1[3]);
                float s10 = dot4(t1q[0], wg0[0]) + dot4(t1q[1], wg0[1])
                          + dot4(t1q[2], wg0[2]) + dot4(t1q[3], wg0[3]);
                float s11 = dot4(t1q[0], wg1[0]) + dot4(t1q[1], wg1[1])
                          + dot4(t1q[2], wg1[2]) + dot4(t1q[3], wg1[3]);
                float4 o;
                o.x = mm / (1.f + __expf(-s00));
                o.y = mm / (1.f + __expf(-s01));
                o.z = mm / (1.f + __expf(-s10));
                o.w = mm / (1.f + __expf(-s11));
                *(float4*)&out[((b * G + d) * G + hh) * G + 4 * pxq] = o;
            }
        }
    }
}

extern "C" void kernel_launch(void* const* d_in, const int* in_sizes, int n_in,
                              void* d_out, int out_size, void* d_ws, size_t ws_size,
                              hipStream_t stream) {
    (void)in_sizes; (void)n_in; (void)out_size; (void)ws_size;
    const float* x   = (const float*)d_in[0];
    const float* W1  = (const float*)d_in[1];
    const float* W2  = (const float*)d_in[2];
    const float* Wt1 = (const float*)d_in[3];
    const float* Wt2 = (const float*)d_in[4];
    const int*   occ = (const int*)d_in[5];
    float* out = (float*)d_out;

    char* ws = (char*)d_ws;
    __half* h1p = (__half*)ws;                                  // 16 MB
    float*  m1  = (float*)(ws + 8388608ull * sizeof(__half));   // 2 MB
    __half* w2h = (__half*)(m1 + 524288);                       // 3456 B
    __half* w1h = w2h + 1728;                                   // 864 B

    k_prep<<<dim3(4), dim3(256), 0, stream>>>(W1, W2, w1h, w2h);
    k_conv1_pool<<<dim3(8, 8, 32), dim3(256), 0, stream>>>(x, occ, (const h2_t*)w1h, h1p, m1);
    k_conv2_dec<<<dim3(8, 8, 16), dim3(256), 0, stream>>>(h1p, m1, (const h2_t*)w2h, Wt1, Wt2, out);
}